// Round 1
// baseline (344.952 us; speedup 1.0000x reference)
//
#include <hip/hip_runtime.h>
#include <hip/hip_bf16.h>

#define DH 32
#define BN 64   // nodes per block in node_proj
#define GN 8    // nodes per 32-lane group
#define NG 8    // groups per block (256/32)

// ---------------------------------------------------------------------------
// Zero agg (as uint bit pattern, 0u == 0.0f) and deg. Must run every call
// (harness does not re-poison ws between replays, and we must be idempotent).
// ---------------------------------------------------------------------------
__global__ __launch_bounds__(256) void init_ws(unsigned* __restrict__ agg_u,
                                               int* __restrict__ deg, int N) {
    int i = blockIdx.x * blockDim.x + threadIdx.x;
    if (i < N * DH) agg_u[i] = 0u;
    if (i < N) deg[i] = 0;
}

// ---------------------------------------------------------------------------
// h = feat @ W_in + b_in            [N,128]@[128,32]
// u = sigmoid(h @ W_nbr + b_nbr + b_neighbor1)   [N,32]@[32,32]
// 64 nodes/block; 8 groups of 32 lanes; each lane owns one output channel c
// and accumulates 8 nodes to amortize LDS traffic.
// ---------------------------------------------------------------------------
__global__ __launch_bounds__(256) void node_proj(
    const float* __restrict__ feat,
    const float* __restrict__ W_in, const float* __restrict__ b_in,
    const float* __restrict__ W_nbr, const float* __restrict__ b_nbr,
    const float* __restrict__ b_n1,
    float* __restrict__ h, float* __restrict__ u, int N)
{
    __shared__ float sfeat[BN * 128];      // 32 KB
    __shared__ float sWt_in[32 * 132];     // Wt[c][k], padded stride 132 (16.9 KB)
    __shared__ float sWt_nbr[32 * 36];     // Wt[c][k], padded stride 36  (4.6 KB)
    __shared__ float sh[BN * 32];          // 8 KB
    __shared__ float sb_in[32], sb2[32];

    const int tid = threadIdx.x;
    const int base = blockIdx.x * BN;

    // stage transposed weights
    for (int i = tid; i < 128 * 32; i += 256) {
        int k = i >> 5, c = i & 31;
        sWt_in[c * 132 + k] = W_in[i];
    }
    for (int i = tid; i < 32 * 32; i += 256) {
        int k = i >> 5, c = i & 31;
        sWt_nbr[c * 36 + k] = W_nbr[i];
    }
    if (tid < 32) { sb_in[tid] = b_in[tid]; sb2[tid] = b_nbr[tid] + b_n1[tid]; }

    // stage feat rows (coalesced float4)
    for (int i = tid; i < BN * 128 / 4; i += 256) {
        int row = i >> 5;                       // 32 float4 per row
        int node = base + row;
        float4 v = make_float4(0.f, 0.f, 0.f, 0.f);
        if (node < N) v = *(const float4*)&feat[(size_t)node * 128 + (size_t)(i & 31) * 4];
        *(float4*)&sfeat[(size_t)i * 4] = v;
    }
    __syncthreads();

    const int g = tid >> 5, c = tid & 31;

    float acc[GN];
#pragma unroll
    for (int m = 0; m < GN; ++m) acc[m] = sb_in[c];

    const float* wcol = &sWt_in[c * 132];
    for (int kk = 0; kk < 128; kk += 4) {
        float4 w = *(const float4*)&wcol[kk];
#pragma unroll
        for (int m = 0; m < GN; ++m) {
            float4 f = *(const float4*)&sfeat[(g * GN + m) * 128 + kk];
            acc[m] += f.x * w.x + f.y * w.y + f.z * w.z + f.w * w.w;
        }
    }

#pragma unroll
    for (int m = 0; m < GN; ++m) {
        int node = base + g * GN + m;
        sh[(g * GN + m) * 32 + c] = acc[m];
        if (node < N) h[(size_t)node * 32 + c] = acc[m];
    }
    __syncthreads();

    float acc2[GN];
#pragma unroll
    for (int m = 0; m < GN; ++m) acc2[m] = sb2[c];

    const float* wcol2 = &sWt_nbr[c * 36];
    for (int kk = 0; kk < 32; kk += 4) {
        float4 w = *(const float4*)&wcol2[kk];
#pragma unroll
        for (int m = 0; m < GN; ++m) {
            float4 hf = *(const float4*)&sh[(g * GN + m) * 32 + kk];
            acc2[m] += hf.x * w.x + hf.y * w.y + hf.z * w.z + hf.w * w.w;
        }
    }

#pragma unroll
    for (int m = 0; m < GN; ++m) {
        int node = base + g * GN + m;
        if (node < N) {
            float s = 1.0f / (1.0f + __expf(-acc2[m]));
            u[(size_t)node * 32 + c] = s;
        }
    }
}

// ---------------------------------------------------------------------------
// Edge pass: for edge (s,d): agg[d] = max(agg[d], u[s]); agg[s] = max(agg[s], u[d])
// 32 lanes per edge, one channel each. Positive floats order as uints.
// ---------------------------------------------------------------------------
__global__ __launch_bounds__(256) void edge_pass(
    const int* __restrict__ src, const int* __restrict__ dst,
    const float* __restrict__ u,
    unsigned* __restrict__ agg_u, int* __restrict__ deg, int E)
{
    long long gid = (long long)blockIdx.x * blockDim.x + threadIdx.x;
    int e = (int)(gid >> 5);
    int c = (int)(gid & 31);
    if (e >= E) return;
    int s = src[e], d = dst[e];
    float us = u[(size_t)s * DH + c];
    float ud = u[(size_t)d * DH + c];
    atomicMax(&agg_u[(size_t)d * DH + c], __float_as_uint(us));
    atomicMax(&agg_u[(size_t)s * DH + c], __float_as_uint(ud));
    if (c == 0) {
        atomicAdd(&deg[s], 1);
        atomicAdd(&deg[d], 1);
    }
}

// ---------------------------------------------------------------------------
// out = concat(h, agg * (deg>1)) @ W_ffnn + b_ffnn    [N,64]@[64,32]
// ---------------------------------------------------------------------------
__global__ __launch_bounds__(256) void finalize(
    const float* __restrict__ h, const float* __restrict__ agg,
    const int* __restrict__ deg,
    const float* __restrict__ W_ffnn, const float* __restrict__ b_ffnn,
    float* __restrict__ out, int N)
{
    __shared__ float sWt[32 * 68];   // Wt[c][k], k<64, padded stride 68 (8.7 KB)
    __shared__ float sx[8][68];      // per local node: [h(32), agg(32)]
    __shared__ float sb[32];

    const int tid = threadIdx.x;
    for (int i = tid; i < 64 * 32; i += 256) {
        int k = i >> 5, c = i & 31;
        sWt[c * 68 + k] = W_ffnn[i];
    }
    if (tid < 32) sb[tid] = b_ffnn[tid];

    const int g = tid >> 5, c = tid & 31;
    const int node = blockIdx.x * 8 + g;

    float hv = 0.f, av = 0.f;
    int dg = 0;
    if (node < N) {
        hv = h[(size_t)node * DH + c];
        av = agg[(size_t)node * DH + c];
        dg = deg[node];
    }
    if (dg <= 1) av = 0.f;
    sx[g][c] = hv;
    sx[g][32 + c] = av;
    __syncthreads();

    float acc = sb[c];
    const float* wcol = &sWt[c * 68];
#pragma unroll
    for (int kk = 0; kk < 64; kk += 4) {
        float4 w = *(const float4*)&wcol[kk];
        float4 x = *(const float4*)&sx[g][kk];
        acc += x.x * w.x + x.y * w.y + x.z * w.z + x.w * w.w;
    }
    if (node < N) out[(size_t)node * DH + c] = acc;
}

// ---------------------------------------------------------------------------
extern "C" void kernel_launch(void* const* d_in, const int* in_sizes, int n_in,
                              void* d_out, int out_size, void* d_ws, size_t ws_size,
                              hipStream_t stream)
{
    const float* feat   = (const float*)d_in[0];
    const int*   src    = (const int*)d_in[1];
    const int*   dst    = (const int*)d_in[2];
    const float* W_in   = (const float*)d_in[3];
    const float* b_in   = (const float*)d_in[4];
    const float* W_nbr  = (const float*)d_in[5];
    const float* b_nbr  = (const float*)d_in[6];
    const float* b_n1   = (const float*)d_in[7];
    const float* W_ffnn = (const float*)d_in[8];
    const float* b_ffnn = (const float*)d_in[9];
    float* out = (float*)d_out;

    const int N = in_sizes[0] / 128;
    const int E = in_sizes[1];

    float* h   = (float*)d_ws;
    float* u   = h + (size_t)N * DH;
    float* agg = u + (size_t)N * DH;
    int*   deg = (int*)(agg + (size_t)N * DH);

    init_ws<<<(N * DH + 255) / 256, 256, 0, stream>>>((unsigned*)agg, deg, N);
    node_proj<<<(N + BN - 1) / BN, 256, 0, stream>>>(feat, W_in, b_in, W_nbr, b_nbr,
                                                     b_n1, h, u, N);
    edge_pass<<<(int)(((long long)E * 32 + 255) / 256), 256, 0, stream>>>(
        src, dst, u, (unsigned*)agg, deg, E);
    finalize<<<(N + 7) / 8, 256, 0, stream>>>(h, agg, deg, W_ffnn, b_ffnn, out, N);
}